// Round 4
// baseline (493.309 us; speedup 1.0000x reference)
//
#include <hip/hip_runtime.h>

typedef __bf16 bf16;
typedef __bf16 bf16x8 __attribute__((ext_vector_type(8)));
typedef float  f32x4  __attribute__((ext_vector_type(4)));

#define S 512
#define DD 768
#define LL 64
#define BB 4

__device__ __forceinline__ bf16x8 scale_cvt(float4 a, float4 b, float4 ua, float4 ub) {
    bf16x8 p;
    p[0] = (bf16)(a.x * ua.x); p[1] = (bf16)(a.y * ua.y);
    p[2] = (bf16)(a.z * ua.z); p[3] = (bf16)(a.w * ua.w);
    p[4] = (bf16)(b.x * ub.x); p[5] = (bf16)(b.y * ub.y);
    p[6] = (bf16)(b.z * ub.z); p[7] = (bf16)(b.w * ub.w);
    return p;
}

// ---------------- prepass 1: dep fp32 -> bf16 ----------------
__global__ void cvt_dep_kernel(const float* __restrict__ dep, bf16* __restrict__ out) {
    int idx = (blockIdx.x * 256 + threadIdx.x) * 8;
    float4 a = *(const float4*)(dep + idx);
    float4 c = *(const float4*)(dep + idx + 4);
    bf16x8 p;
    p[0] = (bf16)a.x; p[1] = (bf16)a.y; p[2] = (bf16)a.z; p[3] = (bf16)a.w;
    p[4] = (bf16)c.x; p[5] = (bf16)c.y; p[6] = (bf16)c.z; p[7] = (bf16)c.w;
    *(bf16x8*)(out + idx) = p;
}

// ---------------- prepass 2: t2h[b,l,i], t2d'[b,l,o] (+bias) ----------------
__global__ void t2_kernel(const float* __restrict__ head, const float* __restrict__ dep,
                          const float* __restrict__ W, const float* __restrict__ bias,
                          float* __restrict__ t2h, float* __restrict__ t2d) {
    __shared__ float Wl[16][DD];
    __shared__ float red[64][4][16];
    int bid = blockIdx.x;
    int sel = bid >> 7;
    int r   = bid & 127;
    int b   = r >> 5;
    int lg  = (r >> 3) & 3;
    int ic  = r & 7;
    const float* src = sel ? dep : head;
    int t = threadIdx.x;

    for (int l16 = 0; l16 < 16; ++l16) {
        const float* wp = W + (size_t)(lg * 16 + l16) * (2 * DD) + sel * DD;
        Wl[l16][t]       = wp[t];
        Wl[l16][t + 256] = wp[t + 256];
        Wl[l16][t + 512] = wp[t + 512];
    }
    __syncthreads();

    int iq = t >> 2, dq = t & 3;
    int i  = ic * 64 + iq;
    const float* rowp = src + (size_t)(b * S + i) * DD;
    float acc[16];
#pragma unroll
    for (int l16 = 0; l16 < 16; ++l16) acc[l16] = 0.f;
    for (int it = 0; it < 48; ++it) {
        int d = dq * 4 + it * 16;
        float4 x = *(const float4*)(rowp + d);
#pragma unroll
        for (int l16 = 0; l16 < 16; ++l16) {
            float4 wv = *(const float4*)&Wl[l16][d];
            acc[l16] += x.x * wv.x + x.y * wv.y + x.z * wv.z + x.w * wv.w;
        }
    }
#pragma unroll
    for (int l16 = 0; l16 < 16; ++l16) red[iq][dq][l16] = acc[l16];
    __syncthreads();

    int iq2 = t >> 2, l4 = t & 3;
    float* dst = sel ? t2d : t2h;
#pragma unroll
    for (int j = 0; j < 4; ++j) {
        int l16 = l4 * 4 + j;
        float v = red[iq2][0][l16] + red[iq2][1][l16] + red[iq2][2][l16] + red[iq2][3][l16];
        if (sel) v += bias[lg * 16 + l16];
        dst[(size_t)(b * LL + lg * 16 + l16) * S + ic * 64 + iq2] = v;
    }
}

// ---------------- main: 128x128 tile, BK=32, 4 waves ----------------
// A (head*U, bf16) staged in dbuf LDS (round-2 scheme, distance-1 reg prefetch).
// B fragments loaded DIRECTLY from depb (L2-resident, 3MB): frag = 16B contiguous
// bf16x8 at [row, kt*32+q*8] — no LDS, no swizzle, no scale. LDS traffic/step
// halves (48KB -> 24KB) and LDS shrinks to ~19.4KB -> more resident blocks.
__global__ __launch_bounds__(256, 4) void biaffine_main(
    const float* __restrict__ head, const bf16* __restrict__ depb,
    const float* __restrict__ U, const float* __restrict__ t2h,
    const float* __restrict__ t2d, float* __restrict__ out) {
    __shared__ __align__(16) bf16 As[2][128][32];
    __shared__ __align__(16) float Ulds[DD];

    const int tid  = threadIdx.x;
    const int lane = tid & 63;
    const int w    = tid >> 6;
    const int bi0  = (blockIdx.x & 3) << 7;
    const int bo0  = (blockIdx.x >> 2) << 7;
    const int l    = blockIdx.y;
    const int b    = blockIdx.z;

    bf16* AsB = &As[0][0][0];

    {   // stage U[l] (768 f32)
        const float* up = U + (size_t)l * DD;
        Ulds[tid]       = up[tid];
        Ulds[tid + 256] = up[tid + 256];
        Ulds[tid + 512] = up[tid + 512];
    }

    // A staging: thread handles rows r1 and r1+64; phys slot cp holds data chunk ca = cp^sw
    const int r1 = tid >> 2;
    const int cp = tid & 3;
    const int sw = (r1 >> 1) & 3;          // same for r1 and r1+64
    const int ca = cp ^ sw;
    const float* hp0 = head + (size_t)(b * S + bi0 + r1) * DD + ca * 8;
    const float* hp1 = hp0 + (size_t)64 * DD;
    const int aoff0 = r1 * 32 + cp * 8;
    const int aoff1 = (r1 + 64) * 32 + cp * 8;

    // fragment geometry
    const int wr = w & 1, wc = w >> 1;
    const int mrow = lane & 15, q = lane >> 4;

    // A fragment LDS element offsets (swizzled, constant across K loop)
    int aFo[4];
#pragma unroll
    for (int mi = 0; mi < 4; ++mi) {
        int rowA = wr * 64 + mi * 16 + mrow;
        aFo[mi] = rowA * 32 + ((q ^ ((rowA >> 1) & 3)) * 8);
    }

    // B fragment global pointers (L2-hot depb); advance by 32 elems per K-step
    const bf16* bgf0 = depb + (size_t)(b * S + bo0 + wc * 64 +  0 + mrow) * DD + q * 8;
    const bf16* bgf1 = depb + (size_t)(b * S + bo0 + wc * 64 + 16 + mrow) * DD + q * 8;
    const bf16* bgf2 = depb + (size_t)(b * S + bo0 + wc * 64 + 32 + mrow) * DD + q * 8;
    const bf16* bgf3 = depb + (size_t)(b * S + bo0 + wc * 64 + 48 + mrow) * DD + q * 8;

    f32x4 acc[4][4];
#pragma unroll
    for (int mi = 0; mi < 4; ++mi)
#pragma unroll
        for (int ni = 0; ni < 4; ++ni)
            acc[mi][ni] = (f32x4){0.f, 0.f, 0.f, 0.f};

    // ---- prologue: stage A K-step 0 into buffer 0 ----
    float4 h0a = *(const float4*)(hp0);
    float4 h0b = *(const float4*)(hp0 + 4);
    float4 h1a = *(const float4*)(hp1);
    float4 h1b = *(const float4*)(hp1 + 4);
    __syncthreads();               // Ulds visible
    {
        const float* uu = &Ulds[ca * 8];
        float4 ua = *(const float4*)(uu);
        float4 ub = *(const float4*)(uu + 4);
        *(bf16x8*)(AsB + aoff0) = scale_cvt(h0a, h0b, ua, ub);
        *(bf16x8*)(AsB + aoff1) = scale_cvt(h1a, h1b, ua, ub);
    }
    __syncthreads();               // A K-step 0 staged

    // ---- main loop: compute A-buf (kt&1), stage kt+1 into the other ----
    for (int kt = 0; kt < 24; ++kt) {
        const int coff = (kt & 1) * 4096;
        const int soff = coff ^ 4096;
        const bool st = kt < 23;

        if (st) {   // issue next-step A global loads FIRST (full-step latency cover)
            const float* h0 = hp0 + (kt + 1) * 32;
            const float* h1 = hp1 + (kt + 1) * 32;
            h0a = *(const float4*)(h0);
            h0b = *(const float4*)(h0 + 4);
            h1a = *(const float4*)(h1);
            h1b = *(const float4*)(h1 + 4);
        }

        // B fragments straight from global (issue early; L2-hit latency hides
        // under the A ds_read + lgkm wait and resident-block TLP)
        bf16x8 bfr[4];
        bfr[0] = *(const bf16x8*)(bgf0 + kt * 32);
        bfr[1] = *(const bf16x8*)(bgf1 + kt * 32);
        bfr[2] = *(const bf16x8*)(bgf2 + kt * 32);
        bfr[3] = *(const bf16x8*)(bgf3 + kt * 32);

        bf16x8 af[4];
#pragma unroll
        for (int mi = 0; mi < 4; ++mi) af[mi] = *(const bf16x8*)(AsB + coff + aFo[mi]);

#pragma unroll
        for (int mi = 0; mi < 4; ++mi)
#pragma unroll
            for (int ni = 0; ni < 4; ++ni)
                acc[mi][ni] = __builtin_amdgcn_mfma_f32_16x16x32_bf16(af[mi], bfr[ni], acc[mi][ni], 0, 0, 0);

        if (st) {   // scale + write A for kt+1 (loads had full-step MFMA cover)
            const float* uu = &Ulds[(kt + 1) * 32 + ca * 8];
            float4 ua = *(const float4*)(uu);
            float4 ub = *(const float4*)(uu + 4);
            *(bf16x8*)(AsB + soff + aoff0) = scale_cvt(h0a, h0b, ua, ub);
            *(bf16x8*)(AsB + soff + aoff1) = scale_cvt(h1a, h1b, ua, ub);
        }
        __syncthreads();           // publish A(kt+1); WAR-protect buf just read
    }

    // ---- epilogue: + t2h[row] + t2d'[col] ----
    const size_t bl = (size_t)(b * LL + l);
    const float* t2hp = t2h + bl * S + bi0 + wr * 64;
    const float* t2dp = t2d + bl * S + bo0 + wc * 64;
    float* outbase = out + bl * (size_t)(S * S);
#pragma unroll
    for (int mi = 0; mi < 4; ++mi) {
        float4 th = *(const float4*)&t2hp[mi * 16 + q * 4];
        int row0 = bi0 + wr * 64 + mi * 16 + q * 4;
#pragma unroll
        for (int ni = 0; ni < 4; ++ni) {
            int col = bo0 + wc * 64 + ni * 16 + mrow;
            float td = t2dp[ni * 16 + mrow];
            float* op = outbase + (size_t)row0 * S + col;
            op[0 * S] = acc[mi][ni][0] + th.x + td;
            op[1 * S] = acc[mi][ni][1] + th.y + td;
            op[2 * S] = acc[mi][ni][2] + th.z + td;
            op[3 * S] = acc[mi][ni][3] + th.w + td;
        }
    }
}

extern "C" void kernel_launch(void* const* d_in, const int* in_sizes, int n_in,
                              void* d_out, int out_size, void* d_ws, size_t ws_size,
                              hipStream_t stream) {
    const float* head = (const float*)d_in[0];
    const float* dep  = (const float*)d_in[1];
    const float* U    = (const float*)d_in[2];
    const float* W    = (const float*)d_in[3];
    const float* bias = (const float*)d_in[4];
    float* out = (float*)d_out;

    char*  ws   = (char*)d_ws;
    bf16*  depb = (bf16*)ws;                               // B*S*D*2   = 3,145,728 B
    float* t2h  = (float*)(ws + 3145728);                  // B*L*S*4   =   524,288 B
    float* t2d  = (float*)(ws + 3145728 + 524288);         // B*L*S*4   =   524,288 B

    cvt_dep_kernel<<<768, 256, 0, stream>>>(dep, depb);
    t2_kernel<<<256, 256, 0, stream>>>(head, dep, W, bias, t2h, t2d);
    biaffine_main<<<dim3(16, LL, BB), 256, 0, stream>>>(head, depb, U, t2h, t2d, out);
}

// Round 5
// 469.450 us; speedup vs baseline: 1.0508x; 1.0508x over previous
//
#include <hip/hip_runtime.h>

typedef __bf16 bf16;
typedef __bf16 bf16x8 __attribute__((ext_vector_type(8)));
typedef float  f32x4  __attribute__((ext_vector_type(4)));

#define S 512
#define DD 768
#define LL 64
#define BB 4

__device__ __forceinline__ void async_copy16(const void* g, void* l) {
    __builtin_amdgcn_global_load_lds(
        (const __attribute__((address_space(1))) unsigned int*)g,
        (__attribute__((address_space(3))) unsigned int*)l,
        16, 0, 0);
}

__device__ __forceinline__ bf16x8 scale_cvt(float4 a, float4 b, float4 ua, float4 ub) {
    bf16x8 p;
    p[0] = (bf16)(a.x * ua.x); p[1] = (bf16)(a.y * ua.y);
    p[2] = (bf16)(a.z * ua.z); p[3] = (bf16)(a.w * ua.w);
    p[4] = (bf16)(b.x * ub.x); p[5] = (bf16)(b.y * ub.y);
    p[6] = (bf16)(b.z * ub.z); p[7] = (bf16)(b.w * ub.w);
    return p;
}

// ---------------- prepass 1: dep fp32 -> bf16 ----------------
__global__ void cvt_dep_kernel(const float* __restrict__ dep, bf16* __restrict__ out) {
    int idx = (blockIdx.x * 256 + threadIdx.x) * 8;
    float4 a = *(const float4*)(dep + idx);
    float4 c = *(const float4*)(dep + idx + 4);
    bf16x8 p;
    p[0] = (bf16)a.x; p[1] = (bf16)a.y; p[2] = (bf16)a.z; p[3] = (bf16)a.w;
    p[4] = (bf16)c.x; p[5] = (bf16)c.y; p[6] = (bf16)c.z; p[7] = (bf16)c.w;
    *(bf16x8*)(out + idx) = p;
}

// ---------------- prepass 2: t2h[b,l,i], t2d'[b,l,o] (+bias) ----------------
__global__ void t2_kernel(const float* __restrict__ head, const float* __restrict__ dep,
                          const float* __restrict__ W, const float* __restrict__ bias,
                          float* __restrict__ t2h, float* __restrict__ t2d) {
    __shared__ float Wl[16][DD];
    __shared__ float red[64][4][16];
    int bid = blockIdx.x;
    int sel = bid >> 7;
    int r   = bid & 127;
    int b   = r >> 5;
    int lg  = (r >> 3) & 3;
    int ic  = r & 7;
    const float* src = sel ? dep : head;
    int t = threadIdx.x;

    for (int l16 = 0; l16 < 16; ++l16) {
        const float* wp = W + (size_t)(lg * 16 + l16) * (2 * DD) + sel * DD;
        Wl[l16][t]       = wp[t];
        Wl[l16][t + 256] = wp[t + 256];
        Wl[l16][t + 512] = wp[t + 512];
    }
    __syncthreads();

    int iq = t >> 2, dq = t & 3;
    int i  = ic * 64 + iq;
    const float* rowp = src + (size_t)(b * S + i) * DD;
    float acc[16];
#pragma unroll
    for (int l16 = 0; l16 < 16; ++l16) acc[l16] = 0.f;
    for (int it = 0; it < 48; ++it) {
        int d = dq * 4 + it * 16;
        float4 x = *(const float4*)(rowp + d);
#pragma unroll
        for (int l16 = 0; l16 < 16; ++l16) {
            float4 wv = *(const float4*)&Wl[l16][d];
            acc[l16] += x.x * wv.x + x.y * wv.y + x.z * wv.z + x.w * wv.w;
        }
    }
#pragma unroll
    for (int l16 = 0; l16 < 16; ++l16) red[iq][dq][l16] = acc[l16];
    __syncthreads();

    int iq2 = t >> 2, l4 = t & 3;
    float* dst = sel ? t2d : t2h;
#pragma unroll
    for (int j = 0; j < 4; ++j) {
        int l16 = l4 * 4 + j;
        float v = red[iq2][0][l16] + red[iq2][1][l16] + red[iq2][2][l16] + red[iq2][3][l16];
        if (sel) v += bias[lg * 16 + l16];
        dst[(size_t)(b * LL + lg * 16 + l16) * S + ic * 64 + iq2] = v;
    }
}

// ---------------- main: 128x128 tile, BK=32, 4 waves, dbuf, 1 sync/K-step ----------------
// R2 (verified-best) structure. Change vs R2: U[l] is read from GLOBAL (L1-resident 3KB row,
// distance-1 reg prefetch like head) instead of LDS -> LDS shrinks 35KB -> 32KB exactly,
// raising residency 4 -> 5 blocks/CU (the measured scaling lever in this latency-bound regime).
__global__ __launch_bounds__(256, 5) void biaffine_main(
    const float* __restrict__ head, const bf16* __restrict__ depb,
    const float* __restrict__ U, const float* __restrict__ t2h,
    const float* __restrict__ t2d, float* __restrict__ out) {
    __shared__ __align__(16) bf16 As[2][128][32];
    __shared__ __align__(16) bf16 Bs[2][128][32];

    const int tid  = threadIdx.x;
    const int lane = tid & 63;
    const int w    = tid >> 6;
    const int bi0  = (blockIdx.x & 3) << 7;
    const int bo0  = (blockIdx.x >> 2) << 7;
    const int l    = blockIdx.y;
    const int b    = blockIdx.z;

    bf16* AsB = &As[0][0][0];
    bf16* BsB = &Bs[0][0][0];

    // A staging: thread handles rows r1 and r1+64; phys slot cp holds data chunk ca = cp^sw
    const int r1 = tid >> 2;
    const int cp = tid & 3;
    const int sw = (r1 >> 1) & 3;          // same for r1 and r1+64
    const int ca = cp ^ sw;
    const float* hp0 = head + (size_t)(b * S + bi0 + r1) * DD + ca * 8;
    const float* hp1 = hp0 + (size_t)64 * DD;
    const float* Up  = U + (size_t)l * DD + ca * 8;   // per-thread U slice base (L1-hot)
    const int aoff0 = r1 * 32 + cp * 8;
    const int aoff1 = (r1 + 64) * 32 + cp * 8;

    // B staging via global_load_lds: 2 insts/wave, 16 rows each, swizzle in global addr
    const int rB0 = w * 32 + (lane >> 2);
    const int rB1 = rB0 + 16;
    const int cpB = lane & 3;
    const bf16* bg0 = depb + (size_t)(b * S + bo0 + rB0) * DD + (cpB ^ ((rB0 >> 1) & 3)) * 8;
    const bf16* bg1 = depb + (size_t)(b * S + bo0 + rB1) * DD + (cpB ^ ((rB1 >> 1) & 3)) * 8;
    const int boff0 = (w * 32) * 32;       // wave-uniform LDS element offsets
    const int boff1 = (w * 32 + 16) * 32;

    // fragment element offsets (constant across K loop)
    const int wr = w & 1, wc = w >> 1;
    const int mrow = lane & 15, q = lane >> 4;
    int aFo[4], bFo[4];
#pragma unroll
    for (int mi = 0; mi < 4; ++mi) {
        int rowA = wr * 64 + mi * 16 + mrow;
        aFo[mi] = rowA * 32 + ((q ^ ((rowA >> 1) & 3)) * 8);
        int rowB = wc * 64 + mi * 16 + mrow;
        bFo[mi] = rowB * 32 + ((q ^ ((rowB >> 1) & 3)) * 8);
    }

    f32x4 acc[4][4];
#pragma unroll
    for (int mi = 0; mi < 4; ++mi)
#pragma unroll
        for (int ni = 0; ni < 4; ++ni)
            acc[mi][ni] = (f32x4){0.f, 0.f, 0.f, 0.f};

    // ---- prologue: stage K-step 0 into buffer 0 ----
    async_copy16(bg0, BsB + boff0);
    async_copy16(bg1, BsB + boff1);
    float4 h0a = *(const float4*)(hp0);
    float4 h0b = *(const float4*)(hp0 + 4);
    float4 h1a = *(const float4*)(hp1);
    float4 h1b = *(const float4*)(hp1 + 4);
    float4 uA  = *(const float4*)(Up);
    float4 uB  = *(const float4*)(Up + 4);
    *(bf16x8*)(AsB + aoff0) = scale_cvt(h0a, h0b, uA, uB);
    *(bf16x8*)(AsB + aoff1) = scale_cvt(h1a, h1b, uA, uB);
    __syncthreads();               // drains B(0) glds; publishes A(0)

    // ---- main loop: compute buf (kt&1), stage kt+1 into the other ----
    for (int kt = 0; kt < 24; ++kt) {
        const int coff = (kt & 1) * 4096;
        const int soff = coff ^ 4096;
        const bool st = kt < 23;

        if (st) {   // issue next-step loads FIRST; gld_lds oldest in VMEM queue
            async_copy16(bg0 + (kt + 1) * 32, BsB + soff + boff0);
            async_copy16(bg1 + (kt + 1) * 32, BsB + soff + boff1);
            const float* h0 = hp0 + (kt + 1) * 32;
            const float* h1 = hp1 + (kt + 1) * 32;
            h0a = *(const float4*)(h0);
            h0b = *(const float4*)(h0 + 4);
            h1a = *(const float4*)(h1);
            h1b = *(const float4*)(h1 + 4);
            uA  = *(const float4*)(Up + (kt + 1) * 32);
            uB  = *(const float4*)(Up + (kt + 1) * 32 + 4);
        }

        bf16x8 af[4], bfr[4];
#pragma unroll
        for (int mi = 0; mi < 4; ++mi) af[mi]  = *(const bf16x8*)(AsB + coff + aFo[mi]);
#pragma unroll
        for (int ni = 0; ni < 4; ++ni) bfr[ni] = *(const bf16x8*)(BsB + coff + bFo[ni]);
#pragma unroll
        for (int mi = 0; mi < 4; ++mi)
#pragma unroll
            for (int ni = 0; ni < 4; ++ni)
                acc[mi][ni] = __builtin_amdgcn_mfma_f32_16x16x32_bf16(af[mi], bfr[ni], acc[mi][ni], 0, 0, 0);

        if (st) {   // scale + write A for kt+1 (loads had full-step MFMA cover)
            *(bf16x8*)(AsB + soff + aoff0) = scale_cvt(h0a, h0b, uA, uB);
            *(bf16x8*)(AsB + soff + aoff1) = scale_cvt(h1a, h1b, uA, uB);
        }
        __syncthreads();           // one drain+publish per K-step
    }

    // ---- epilogue: + t2h[row] + t2d'[col] ----
    const size_t bl = (size_t)(b * LL + l);
    const float* t2hp = t2h + bl * S + bi0 + wr * 64;
    const float* t2dp = t2d + bl * S + bo0 + wc * 64;
    float* outbase = out + bl * (size_t)(S * S);
#pragma unroll
    for (int mi = 0; mi < 4; ++mi) {
        float4 th = *(const float4*)&t2hp[mi * 16 + q * 4];
        int row0 = bi0 + wr * 64 + mi * 16 + q * 4;
#pragma unroll
        for (int ni = 0; ni < 4; ++ni) {
            int col = bo0 + wc * 64 + ni * 16 + mrow;
            float td = t2dp[ni * 16 + mrow];
            float* op = outbase + (size_t)row0 * S + col;
            op[0 * S] = acc[mi][ni][0] + th.x + td;
            op[1 * S] = acc[mi][ni][1] + th.y + td;
            op[2 * S] = acc[mi][ni][2] + th.z + td;
            op[3 * S] = acc[mi][ni][3] + th.w + td;
        }
    }
}

extern "C" void kernel_launch(void* const* d_in, const int* in_sizes, int n_in,
                              void* d_out, int out_size, void* d_ws, size_t ws_size,
                              hipStream_t stream) {
    const float* head = (const float*)d_in[0];
    const float* dep  = (const float*)d_in[1];
    const float* U    = (const float*)d_in[2];
    const float* W    = (const float*)d_in[3];
    const float* bias = (const float*)d_in[4];
    float* out = (float*)d_out;

    char*  ws   = (char*)d_ws;
    bf16*  depb = (bf16*)ws;                               // B*S*D*2   = 3,145,728 B
    float* t2h  = (float*)(ws + 3145728);                  // B*L*S*4   =   524,288 B
    float* t2d  = (float*)(ws + 3145728 + 524288);         // B*L*S*4   =   524,288 B

    cvt_dep_kernel<<<768, 256, 0, stream>>>(dep, depb);
    t2_kernel<<<256, 256, 0, stream>>>(head, dep, W, bias, t2h, t2d);
    biaffine_main<<<dim3(16, LL, BB), 256, 0, stream>>>(head, depb, U, t2h, t2d, out);
}